// Round 1
// baseline (669.098 us; speedup 1.0000x reference)
//
#include <hip/hip_runtime.h>
#include <hip/hip_bf16.h>

#define CIN  32
#define COUT 64
#define RNK  64
#define HD   64           // H = W = D = 64
#define TH   4
#define TW   4
#define TD   16
#define PH   (TH + 2)     // 6
#define PW   (TW + 2)     // 6
#define PD   (TD + 2)     // 18
#define NPAD (PH * PW * PD)   // 648
#define RC   8                 // rank chunk
#define NCHUNK (RNK / RC)      // 8
#define T1N  (TH * PW * PD)    // 432
#define T2N  (TH * TW * PD)    // 288
#define T3N  (TH * TW * TD)    // 256
#define NTHREADS 512

__global__ __launch_bounds__(NTHREADS, 4)
void cpd_conv3d_fused(const float* __restrict__ x,
                      const float* __restrict__ Ukh,
                      const float* __restrict__ Ukw,
                      const float* __restrict__ Ukd,
                      const float* __restrict__ Ucin,
                      const float* __restrict__ Uco,
                      const float* __restrict__ bias,
                      float* __restrict__ out)
{
    __shared__ __hip_bfloat16 xs[CIN * NPAD];   // 41472 B
    __shared__ __hip_bfloat16 t0[RC * NPAD];    // 10368 B (reused as t2)
    __shared__ __hip_bfloat16 t1[RC * T1N];     //  6912 B (reused as t3)
    __shared__ float uk[9 * RNK];               //  2304 B  (ukh|ukw|ukd)

    __hip_bfloat16* t2 = t0;   // RC*T2N = 2304 <= RC*NPAD ✓
    __hip_bfloat16* t3 = t1;   // RC*T3N = 2048 <= RC*T1N ✓

    const int tid = threadIdx.x;
    const int bid = blockIdx.x;
    const int dt = bid & 3;
    const int wt = (bid >> 2) & 15;
    const int ht = (bid >> 6) & 15;
    const int b  = bid >> 10;
    const int h0 = ht * TH, w0 = wt * TW, d0 = dt * TD;

    // ---- load small weights into LDS ----
    for (int i = tid; i < 3 * RNK; i += NTHREADS) {
        uk[i]           = Ukh[i];
        uk[3 * RNK + i] = Ukw[i];
        uk[6 * RNK + i] = Ukd[i];
    }

    // ---- stage padded x tile (bf16) ----
    const long xbase = (long)b * CIN * (1 << 18);
    for (int c = 0; c < CIN; ++c) {
        for (int pp = tid; pp < NPAD; pp += NTHREADS) {
            int ph  = pp / (PW * PD);
            int rem = pp - ph * (PW * PD);
            int pw  = rem / PD;
            int pd  = rem - pw * PD;
            int gh = h0 + ph - 1;
            int gw = w0 + pw - 1;
            int gd = d0 + pd - 1;
            float v = 0.f;
            if ((unsigned)gh < HD && (unsigned)gw < HD && (unsigned)gd < HD) {
                v = x[xbase + ((long)c << 18) + (gh << 12) + (gw << 6) + gd];
            }
            xs[c * NPAD + pp] = __float2bfloat16(v);
        }
    }
    __syncthreads();

    // out accumulator: thread owns voxel p (0..255) and co-half (tid>>8)
    const int p    = tid & (T3N - 1);
    const int half = tid >> 8;          // wave-uniform → Uco reads stay scalar
    float acc_out[32];
#pragma unroll
    for (int i = 0; i < 32; ++i) acc_out[i] = 0.f;

    for (int rc = 0; rc < NCHUNK; ++rc) {
        const int rbase = rc * RC;

        // 2a: channel contraction  t0[j][pp] = sum_c xs[c][pp] * Ucin[c][rbase+j]
        for (int pp = tid; pp < NPAD; pp += NTHREADS) {
            float acc[RC];
#pragma unroll
            for (int j = 0; j < RC; ++j) acc[j] = 0.f;
#pragma unroll 8
            for (int c = 0; c < CIN; ++c) {
                float xv = (float)xs[c * NPAD + pp];
                const float* ucp = &Ucin[c * RNK + rbase];
#pragma unroll
                for (int j = 0; j < RC; ++j)
                    acc[j] += xv * ucp[j];
            }
#pragma unroll
            for (int j = 0; j < RC; ++j)
                t0[j * NPAD + pp] = __float2bfloat16(acc[j]);
        }
        __syncthreads();

        // 2b: h-conv  t1[j][q] = sum_k t0[j][q + k*(PW*PD)] * ukh[k][r]
        for (int idx = tid; idx < RC * T1N; idx += NTHREADS) {
            int j = idx / T1N;
            int q = idx - j * T1N;
            float wa = uk[0 * RNK + rbase + j];
            float wb = uk[1 * RNK + rbase + j];
            float wc = uk[2 * RNK + rbase + j];
            int s = j * NPAD + q;
            float v = wa * (float)t0[s]
                    + wb * (float)t0[s + PW * PD]
                    + wc * (float)t0[s + 2 * PW * PD];
            t1[idx] = __float2bfloat16(v);
        }
        __syncthreads();

        // 2c: w-conv  t2[j][oh][ow][pd] = sum_k t1[j][oh][ow+k][pd] * ukw[k][r]
        for (int idx = tid; idx < RC * T2N; idx += NTHREADS) {
            int j   = idx / T2N;
            int q2  = idx - j * T2N;
            int oh  = q2 / (TW * PD);
            int rem = q2 - oh * (TW * PD);
            int s = j * T1N + oh * (PW * PD) + rem;
            float wa = uk[3 * RNK + rbase + j];
            float wb = uk[4 * RNK + rbase + j];
            float wc = uk[5 * RNK + rbase + j];
            float v = wa * (float)t1[s]
                    + wb * (float)t1[s + PD]
                    + wc * (float)t1[s + 2 * PD];
            t2[idx] = __float2bfloat16(v);
        }
        __syncthreads();

        // 2d: d-conv  t3[j][oh][ow][od] = sum_k t2[j][oh][ow][od+k] * ukd[k][r]
        for (int idx = tid; idx < RC * T3N; idx += NTHREADS) {
            int j  = idx >> 8;          // T3N = 256
            int q3 = idx & (T3N - 1);
            int oh = q3 >> 6;
            int ow = (q3 >> 4) & 3;
            int od = q3 & 15;
            int s = j * T2N + oh * (TW * PD) + ow * PD + od;
            float wa = uk[6 * RNK + rbase + j];
            float wb = uk[7 * RNK + rbase + j];
            float wc = uk[8 * RNK + rbase + j];
            float v = wa * (float)t2[s]
                    + wb * (float)t2[s + 1]
                    + wc * (float)t2[s + 2];
            t3[idx] = __float2bfloat16(v);
        }
        __syncthreads();

        // 2e: out GEMM accumulate  acc_out[co] += t3[j][p] * Uco[r][half*32+co]
#pragma unroll
        for (int j = 0; j < RC; ++j) {
            float v = (float)t3[j * T3N + p];
            const float* up = &Uco[(rbase + j) * COUT + half * 32];
#pragma unroll
            for (int co = 0; co < 32; ++co)
                acc_out[co] += v * up[co];
        }
        __syncthreads();
    }

    // ---- epilogue: bias + store ----
    {
        int oh = p >> 6, ow = (p >> 4) & 3, od = p & 15;
        int h = h0 + oh, w = w0 + ow, d = d0 + od;
        int sp = (h << 12) + (w << 6) + d;
        const long obase = ((long)(b * COUT)) << 18;
#pragma unroll
        for (int co = 0; co < 32; ++co) {
            int c = half * 32 + co;
            out[obase + ((long)c << 18) + sp] = acc_out[co] + bias[c];
        }
    }
}

extern "C" void kernel_launch(void* const* d_in, const int* in_sizes, int n_in,
                              void* d_out, int out_size, void* d_ws, size_t ws_size,
                              hipStream_t stream) {
    const float* x    = (const float*)d_in[0];
    const float* Ukh  = (const float*)d_in[1];
    const float* Ukw  = (const float*)d_in[2];
    const float* Ukd  = (const float*)d_in[3];
    const float* Ucin = (const float*)d_in[4];
    const float* Uco  = (const float*)d_in[5];
    const float* bias = (const float*)d_in[6];
    float* out = (float*)d_out;

    // grid: 2 batches * 16 h-tiles * 16 w-tiles * 4 d-tiles = 2048 blocks
    cpd_conv3d_fused<<<2048, NTHREADS, 0, stream>>>(
        x, Ukh, Ukw, Ukd, Ucin, Uco, bias, out);
}

// Round 2
// 424.625 us; speedup vs baseline: 1.5757x; 1.5757x over previous
//
#include <hip/hip_runtime.h>
#include <hip/hip_bf16.h>

typedef __attribute__((ext_vector_type(8))) short short8;
typedef __attribute__((ext_vector_type(4))) float f32x4;

#define NTH 512
#define NPADP 656          // 648 real padded positions + 8 pad rows (41 m-tiles)
#define SMEM_BYTES ((NPADP*32 + NPADP*32 + 432*32 + 64*32 + 64*64)*2 + 576*4)  // 126208

__device__ __forceinline__ float b2f(short s) {
    return __uint_as_float(((unsigned int)(unsigned short)s) << 16);
}
__device__ __forceinline__ short f2b(float f) {
    unsigned int u = __float_as_uint(f);
    u += 0x7fffu + ((u >> 16) & 1u);       // RNE
    return (short)(u >> 16);
}

__global__ __launch_bounds__(NTH)
void cpd_conv3d_mfma(const float* __restrict__ x,
                     const float* __restrict__ Ukh,
                     const float* __restrict__ Ukw,
                     const float* __restrict__ Ukd,
                     const float* __restrict__ Ucin,
                     const float* __restrict__ Uco,
                     const float* __restrict__ bias,
                     float* __restrict__ out)
{
    extern __shared__ char smem[];
    short* xs   = (short*)smem;            // [656][32]  bf16, A of GEMM1
    short* t0   = xs   + NPADP*32;         // [656][32]  t0 / t2 (w-conv out)
    short* t1   = t0   + NPADP*32;         // [432][32]  t1 / t3 (d-conv out)
    short* uct  = t1   + 432*32;           // [64][32]   Ucin^T
    short* ucot = uct  + 64*32;            // [64][64]   Uco^T
    float* ukf  = (float*)(ucot + 64*64);  // [9][64]    ukh|ukw|ukd fp32

    const int tid  = threadIdx.x;
    const int lane = tid & 63;
    const int wv   = tid >> 6;             // wave 0..7
    const int l15  = lane & 15;
    const int quad = lane >> 4;
    const int rg   = tid & 3;              // conv rank-group (fixed per thread)

    const int bid = blockIdx.x;
    const int dt = bid & 3, wt = (bid >> 2) & 15, ht = (bid >> 6) & 15, b = bid >> 10;
    const int h0 = ht * 4, w0 = wt * 4, d0 = dt * 16;

    // ---------------- staging ----------------
    for (int i = tid; i < 576; i += NTH) {
        float v = (i < 192) ? Ukh[i] : (i < 384 ? Ukw[i - 192] : Ukd[i - 384]);
        ukf[i] = v;   // rows 0-2: Ukh[k][r]; 3-5: Ukw; 6-8: Ukd
    }
    for (int i = tid; i < 2048; i += NTH) {         // Uct[r][c] = Ucin[c][r]
        int r = i >> 5, c = i & 31;
        uct[i] = f2b(Ucin[c * 64 + r]);
    }
    for (int i = tid; i < 4096; i += NTH) {         // Ucot[co][r] = Uco[r][co]
        int co = i >> 6, r = i & 63;
        ucot[i] = f2b(Uco[r * 64 + co]);
    }
    for (int i = tid; i < NPADP * 32; i += NTH) {   // xs[pp][c]
        int pp = i >> 5, c = i & 31;
        float v = 0.f;
        if (pp < 648) {
            int ph = pp / 108, rem = pp - ph * 108;
            int pw = rem / 18, pd = rem - pw * 18;
            int gh = h0 + ph - 1, gw = w0 + pw - 1, gd = d0 + pd - 1;
            if ((unsigned)gh < 64u && (unsigned)gw < 64u && (unsigned)gd < 64u)
                v = x[((long)(b * 32 + c) << 18) + (gh << 12) + (gw << 6) + gd];
        }
        xs[i] = f2b(v);
    }
    __syncthreads();

    f32x4 acc[8] = {};   // GEMM2 accumulators: 8 tiles/wave

    for (int pass = 0; pass < 2; ++pass) {
        const int rbase = pass * 32;

        // ---- GEMM1 (MFMA): t0[pp][rl] = xs[pp][c] * Ucin[c][rbase+rl] ----
        {
            const int nt = wv & 1;
            short8 bfrag = *(const short8*)&uct[(rbase + nt * 16 + l15) * 32 + quad * 8];
            for (int mt = (wv >> 1); mt <= 40; mt += 4) {
                short8 afrag = *(const short8*)&xs[(mt * 16 + l15) * 32 + quad * 8];
                f32x4 c = {};
                c = __builtin_amdgcn_mfma_f32_16x16x32_bf16(afrag, bfrag, c, 0, 0, 0);
                const int col = nt * 16 + l15;
#pragma unroll
                for (int i2 = 0; i2 < 4; ++i2)
                    t0[(mt * 16 + quad * 4 + i2) * 32 + col] = f2b(c[i2]);
            }
        }
        __syncthreads();

        // ---- h-conv: t1[q][j] = sum_k t0[q + k*108][j] * Ukh[k][r] ----
        {
            float wh[3][8];
#pragma unroll
            for (int k = 0; k < 3; ++k) {
                const float4* p = (const float4*)&ukf[k * 64 + rbase + rg * 8];
                float4 u0 = p[0], u1 = p[1];
                wh[k][0] = u0.x; wh[k][1] = u0.y; wh[k][2] = u0.z; wh[k][3] = u0.w;
                wh[k][4] = u1.x; wh[k][5] = u1.y; wh[k][6] = u1.z; wh[k][7] = u1.w;
            }
            for (int item = tid; item < 1728; item += NTH) {
                int q = item >> 2;
                float v[8] = {};
#pragma unroll
                for (int k = 0; k < 3; ++k) {
                    short8 s = *(const short8*)&t0[(q + k * 108) * 32 + rg * 8];
#pragma unroll
                    for (int j = 0; j < 8; ++j) v[j] += wh[k][j] * b2f(s[j]);
                }
                short8 o;
#pragma unroll
                for (int j = 0; j < 8; ++j) o[j] = f2b(v[j]);
                *(short8*)&t1[q * 32 + rg * 8] = o;
            }
        }
        __syncthreads();

        // ---- w-conv: t2(q2) = sum_k t1[q2 + oh*36 + k*18] ; t2 = t0 region ----
        {
            float ww[3][8];
#pragma unroll
            for (int k = 0; k < 3; ++k) {
                const float4* p = (const float4*)&ukf[(3 + k) * 64 + rbase + rg * 8];
                float4 u0 = p[0], u1 = p[1];
                ww[k][0] = u0.x; ww[k][1] = u0.y; ww[k][2] = u0.z; ww[k][3] = u0.w;
                ww[k][4] = u1.x; ww[k][5] = u1.y; ww[k][6] = u1.z; ww[k][7] = u1.w;
            }
            for (int item = tid; item < 1152; item += NTH) {
                int q2 = item >> 2;
                int oh = q2 / 72;
                int src = q2 + oh * 36;
                float v[8] = {};
#pragma unroll
                for (int k = 0; k < 3; ++k) {
                    short8 s = *(const short8*)&t1[(src + k * 18) * 32 + rg * 8];
#pragma unroll
                    for (int j = 0; j < 8; ++j) v[j] += ww[k][j] * b2f(s[j]);
                }
                short8 o;
#pragma unroll
                for (int j = 0; j < 8; ++j) o[j] = f2b(v[j]);
                *(short8*)&t0[q2 * 32 + rg * 8] = o;
            }
        }
        __syncthreads();

        // ---- d-conv: t3(p) = sum_k t2[p + (p>>4)*2 + k] ; t3 = t1 region ----
        {
            float wd[3][8];
#pragma unroll
            for (int k = 0; k < 3; ++k) {
                const float4* p = (const float4*)&ukf[(6 + k) * 64 + rbase + rg * 8];
                float4 u0 = p[0], u1 = p[1];
                wd[k][0] = u0.x; wd[k][1] = u0.y; wd[k][2] = u0.z; wd[k][3] = u0.w;
                wd[k][4] = u1.x; wd[k][5] = u1.y; wd[k][6] = u1.z; wd[k][7] = u1.w;
            }
            for (int item = tid; item < 1024; item += NTH) {
                int p = item >> 2;
                int src = p + (p >> 4) * 2;
                float v[8] = {};
#pragma unroll
                for (int k = 0; k < 3; ++k) {
                    short8 s = *(const short8*)&t0[(src + k) * 32 + rg * 8];
#pragma unroll
                    for (int j = 0; j < 8; ++j) v[j] += wd[k][j] * b2f(s[j]);
                }
                short8 o;
#pragma unroll
                for (int j = 0; j < 8; ++j) o[j] = f2b(v[j]);
                *(short8*)&t1[p * 32 + rg * 8] = o;
            }
        }
        __syncthreads();

        // ---- GEMM2 (MFMA): acc[m][co] += t3[m][rl] * Uco[rbase+rl][co] ----
        {
            short8 bfr[4];
#pragma unroll
            for (int nt = 0; nt < 4; ++nt)
                bfr[nt] = *(const short8*)&ucot[(nt * 16 + l15) * 64 + rbase + quad * 8];
#pragma unroll
            for (int i = 0; i < 8; ++i) {
                int mt = wv * 2 + (i >> 2), nt = i & 3;
                short8 afr = *(const short8*)&t1[(mt * 16 + l15) * 32 + quad * 8];
                acc[i] = __builtin_amdgcn_mfma_f32_16x16x32_bf16(afr, bfr[nt], acc[i], 0, 0, 0);
            }
        }
        // no barrier needed: next-pass GEMM1 writes t0 only; t1 rewritten
        // only after the sync following GEMM1.
    }

    // ---------------- epilogue: bias + coalesced dwordx4 stores ----------------
#pragma unroll
    for (int i = 0; i < 8; ++i) {
        int mt = wv * 2 + (i >> 2), nt = i & 3;
        int co = nt * 16 + l15;
        int oh = mt >> 2, ow = mt & 3;
        float bs = bias[co];
        float4 o4;
        o4.x = acc[i][0] + bs; o4.y = acc[i][1] + bs;
        o4.z = acc[i][2] + bs; o4.w = acc[i][3] + bs;
        long addr = ((long)(b * 64 + co) << 18) + ((long)(h0 + oh) << 12)
                  + ((w0 + ow) << 6) + (d0 + quad * 4);
        *(float4*)&out[addr] = o4;
    }
}

extern "C" void kernel_launch(void* const* d_in, const int* in_sizes, int n_in,
                              void* d_out, int out_size, void* d_ws, size_t ws_size,
                              hipStream_t stream) {
    const float* x    = (const float*)d_in[0];
    const float* Ukh  = (const float*)d_in[1];
    const float* Ukw  = (const float*)d_in[2];
    const float* Ukd  = (const float*)d_in[3];
    const float* Ucin = (const float*)d_in[4];
    const float* Uco  = (const float*)d_in[5];
    const float* bias = (const float*)d_in[6];
    float* out = (float*)d_out;

    // >64KB dynamic LDS requires the opt-in attribute (idempotent, capture-safe)
    (void)hipFuncSetAttribute((const void*)cpd_conv3d_mfma,
                              hipFuncAttributeMaxDynamicSharedMemorySize,
                              SMEM_BYTES);

    // grid: 2 batches * 16 h * 16 w * 4 d = 2048 blocks
    cpd_conv3d_mfma<<<2048, NTH, SMEM_BYTES, stream>>>(
        x, Ukh, Ukw, Ukd, Ucin, Uco, bias, out);
}

// Round 3
// 324.739 us; speedup vs baseline: 2.0604x; 1.3076x over previous
//
#include <hip/hip_runtime.h>
#include <hip/hip_bf16.h>

typedef __attribute__((ext_vector_type(8))) short short8;
typedef __attribute__((ext_vector_type(4))) float f32x4;

__device__ __forceinline__ float b2f(short s) {
    return __uint_as_float(((unsigned int)(unsigned short)s) << 16);
}
__device__ __forceinline__ short f2b(float f) {
    unsigned int u = __float_as_uint(f);
    u += 0x7fffu + ((u >> 16) & 1u);       // RNE
    return (short)(u >> 16);
}
__device__ __forceinline__ unsigned pack2(float a, float b) {
    return (unsigned)(unsigned short)f2b(a) | ((unsigned)(unsigned short)f2b(b) << 16);
}

// ============================================================================
// K1: channel contraction.  t[b][h][w][d][r] (bf16, r contiguous)
//     t[sp][r] = sum_c x[b][c][sp] * Ucin[c][r]
// No LDS, no barriers. Ucin reads are wave-uniform -> scalar loads.
// ============================================================================
__global__ __launch_bounds__(256)
void k1_channel(const float* __restrict__ x,
                const float* __restrict__ Ucin,
                short* __restrict__ t)
{
    const int gp = blockIdx.x * 256 + threadIdx.x;   // 0 .. 524287
    const int b  = gp >> 18;
    const int sp = gp & 262143;
    const float* xp = x + ((long)b << 23) + sp;

    float acc[64];
#pragma unroll
    for (int r = 0; r < 64; ++r) acc[r] = 0.f;

#pragma unroll 4
    for (int c = 0; c < 32; ++c) {
        float xv = xp[(long)c << 18];
        const float* u = Ucin + c * 64;
#pragma unroll
        for (int r = 0; r < 64; ++r) acc[r] += xv * u[r];
    }

    uint4* dst = (uint4*)(t + (size_t)gp * 64);
#pragma unroll
    for (int j = 0; j < 8; ++j) {
        uint4 o;
        o.x = pack2(acc[8 * j + 0], acc[8 * j + 1]);
        o.y = pack2(acc[8 * j + 2], acc[8 * j + 3]);
        o.z = pack2(acc[8 * j + 4], acc[8 * j + 5]);
        o.w = pack2(acc[8 * j + 6], acc[8 * j + 7]);
        dst[j] = o;
    }
}

// ============================================================================
// K2: one block per (b,h,w) column of 64 d-voxels.
//   phase A: hw-conv (9 fused weights) from 9 neighbor columns (global reads,
//            L2/L3-resident) -> s[66][64] bf16 in LDS (d-padded)
//   phase B: d-conv -> p[64][72] bf16 in LDS (72-stride: conflict-free b128)
//   phase C: out GEMM M=64(d) N=64(co) K=64(r) via mfma_16x16x32_bf16 + bias
// ============================================================================
__global__ __launch_bounds__(256)
void k2_conv_gemm(const short* __restrict__ t,
                  const float* __restrict__ Ukh,
                  const float* __restrict__ Ukw,
                  const float* __restrict__ Ukd,
                  const float* __restrict__ Uco,
                  const float* __restrict__ bias,
                  float* __restrict__ out)
{
    __shared__ short s[66 * 64];      //  8448 B
    __shared__ short p[64 * 72];      //  9216 B
    __shared__ short ucot[64 * 72];   //  9216 B   Uco^T, padded stride

    const int tid = threadIdx.x;

    // XCD-aware swizzle: slot = bid&7 (likely XCD), each slot owns an h-band
    // of 8 rows so neighbor columns (h+-1, w+-1) reuse within one XCD's L2.
    const int bid  = blockIdx.x;              // 8192 = 2b * 64h * 64w
    const int slot = bid & 7;
    const int idx  = bid >> 3;                // 1024 per slot
    const int b    = idx >> 9;
    const int rem  = idx & 511;
    const int h    = slot * 8 + (rem >> 6);
    const int w    = rem & 63;

    // 9 neighbor-column base pointers (element (d,r) at base + d*64 + r).
    // OOB columns: keep a valid pointer, zero the weights (branch-free loads).
    const short* colp[9];
    bool valid[9];
#pragma unroll
    for (int kh = 0; kh < 3; ++kh) {
#pragma unroll
        for (int kw = 0; kw < 3; ++kw) {
            int hh = h + kh - 1, ww = w + kw - 1;
            bool v = ((unsigned)hh < 64u) && ((unsigned)ww < 64u);
            valid[kh * 3 + kw] = v;
            long base = v ? ((long)(b * 262144 + hh * 4096 + ww * 64) << 6) : 0;
            colp[kh * 3 + kw] = t + base;
        }
    }

    // stage Uco^T (coalesced global read, strided LDS write)
    for (int i = tid; i < 4096; i += 256) {
        int r = i >> 6, co = i & 63;
        ucot[co * 72 + r] = f2b(Uco[i]);
    }

    // ---- phase A: hw-conv. thread owns r-quad rq (fixed), iterates sd ----
    const int rq = tid & 15;                  // r = 4*rq .. 4*rq+3
    float4 W[9];
    {
        float4 a[3], c[3];
#pragma unroll
        for (int k = 0; k < 3; ++k) {
            a[k] = *(const float4*)&Ukh[k * 64 + 4 * rq];
            c[k] = *(const float4*)&Ukw[k * 64 + 4 * rq];
        }
#pragma unroll
        for (int kh = 0; kh < 3; ++kh)
#pragma unroll
            for (int kw = 0; kw < 3; ++kw) {
                int kk = kh * 3 + kw;
                float m = valid[kk] ? 1.f : 0.f;
                W[kk].x = a[kh].x * c[kw].x * m;
                W[kk].y = a[kh].y * c[kw].y * m;
                W[kk].z = a[kh].z * c[kw].z * m;
                W[kk].w = a[kh].w * c[kw].w * m;
            }
    }
    for (int it = tid; it < 66 * 16; it += 256) {
        int sd = it >> 4;                     // 0..65, d = sd-1
        int d  = sd - 1;
        float a0 = 0.f, a1 = 0.f, a2 = 0.f, a3 = 0.f;
        if ((unsigned)d < 64u) {
            int off = d * 64 + 4 * rq;
#pragma unroll
            for (int kk = 0; kk < 9; ++kk) {
                uint2 uu = *(const uint2*)(colp[kk] + off);
                a0 += W[kk].x * b2f((short)(uu.x));
                a1 += W[kk].y * b2f((short)(uu.x >> 16));
                a2 += W[kk].z * b2f((short)(uu.y));
                a3 += W[kk].w * b2f((short)(uu.y >> 16));
            }
        }
        uint2 o; o.x = pack2(a0, a1); o.y = pack2(a2, a3);
        *(uint2*)&s[sd * 64 + 4 * rq] = o;
    }
    __syncthreads();

    // ---- phase B: d-conv into p (stride 72) ----
    {
        float4 Wd[3];
#pragma unroll
        for (int k = 0; k < 3; ++k)
            Wd[k] = *(const float4*)&Ukd[k * 64 + 4 * rq];
        for (int u = tid; u < 64 * 16; u += 256) {
            int d = u >> 4;
            float a0 = 0.f, a1 = 0.f, a2 = 0.f, a3 = 0.f;
#pragma unroll
            for (int k = 0; k < 3; ++k) {
                uint2 uu = *(const uint2*)&s[(d + k) * 64 + 4 * rq];
                a0 += Wd[k].x * b2f((short)(uu.x));
                a1 += Wd[k].y * b2f((short)(uu.x >> 16));
                a2 += Wd[k].z * b2f((short)(uu.y));
                a3 += Wd[k].w * b2f((short)(uu.y >> 16));
            }
            uint2 o; o.x = pack2(a0, a1); o.y = pack2(a2, a3);
            *(uint2*)&p[d * 72 + 4 * rq] = o;
        }
    }
    __syncthreads();

    // ---- phase C: out GEMM + bias + store ----
    {
        const int lane = tid & 63, wv = tid >> 6;
        const int l15 = lane & 15, quad = lane >> 4;
        short8 afr0 = *(const short8*)&p[(wv * 16 + l15) * 72 + quad * 8];
        short8 afr1 = *(const short8*)&p[(wv * 16 + l15) * 72 + 32 + quad * 8];
        f32x4 acc[4] = {};
#pragma unroll
        for (int nt = 0; nt < 4; ++nt) {
            short8 b0 = *(const short8*)&ucot[(nt * 16 + l15) * 72 + quad * 8];
            short8 b1 = *(const short8*)&ucot[(nt * 16 + l15) * 72 + 32 + quad * 8];
            acc[nt] = __builtin_amdgcn_mfma_f32_16x16x32_bf16(afr0, b0, acc[nt], 0, 0, 0);
            acc[nt] = __builtin_amdgcn_mfma_f32_16x16x32_bf16(afr1, b1, acc[nt], 0, 0, 0);
        }
#pragma unroll
        for (int nt = 0; nt < 4; ++nt) {
            int co = nt * 16 + l15;
            float bs = bias[co];
            int d = wv * 16 + quad * 4;
            float4 o;
            o.x = acc[nt][0] + bs; o.y = acc[nt][1] + bs;
            o.z = acc[nt][2] + bs; o.w = acc[nt][3] + bs;
            long addr = ((long)(b * 64 + co) << 18) + (h << 12) + (w << 6) + d;
            *(float4*)&out[addr] = o;
        }
    }
}

// ============================================================================
// Fallback (round-2 fused kernel) if workspace is too small for t.
// ============================================================================
#define NTH 512
#define NPADP 656
#define SMEM_BYTES ((NPADP*32 + NPADP*32 + 432*32 + 64*32 + 64*64)*2 + 576*4)

__global__ __launch_bounds__(NTH)
void cpd_conv3d_fused_fb(const float* __restrict__ x,
                         const float* __restrict__ Ukh,
                         const float* __restrict__ Ukw,
                         const float* __restrict__ Ukd,
                         const float* __restrict__ Ucin,
                         const float* __restrict__ Uco,
                         const float* __restrict__ bias,
                         float* __restrict__ out)
{
    extern __shared__ char smem[];
    short* xs   = (short*)smem;
    short* t0   = xs   + NPADP*32;
    short* t1   = t0   + NPADP*32;
    short* uct  = t1   + 432*32;
    short* ucot = uct  + 64*32;
    float* ukf  = (float*)(ucot + 64*64);

    const int tid  = threadIdx.x;
    const int lane = tid & 63;
    const int wv   = tid >> 6;
    const int l15  = lane & 15;
    const int quad = lane >> 4;
    const int rg   = tid & 3;

    const int bid = blockIdx.x;
    const int dt = bid & 3, wt = (bid >> 2) & 15, ht = (bid >> 6) & 15, b = bid >> 10;
    const int h0 = ht * 4, w0 = wt * 4, d0 = dt * 16;

    for (int i = tid; i < 576; i += NTH) {
        float v = (i < 192) ? Ukh[i] : (i < 384 ? Ukw[i - 192] : Ukd[i - 384]);
        ukf[i] = v;
    }
    for (int i = tid; i < 2048; i += NTH) {
        int r = i >> 5, c = i & 31;
        uct[i] = f2b(Ucin[c * 64 + r]);
    }
    for (int i = tid; i < 4096; i += NTH) {
        int co = i >> 6, r = i & 63;
        ucot[i] = f2b(Uco[r * 64 + co]);
    }
    for (int i = tid; i < NPADP * 32; i += NTH) {
        int pp = i >> 5, c = i & 31;
        float v = 0.f;
        if (pp < 648) {
            int ph = pp / 108, rem = pp - ph * 108;
            int pw = rem / 18, pd = rem - pw * 18;
            int gh = h0 + ph - 1, gw = w0 + pw - 1, gd = d0 + pd - 1;
            if ((unsigned)gh < 64u && (unsigned)gw < 64u && (unsigned)gd < 64u)
                v = x[((long)(b * 32 + c) << 18) + (gh << 12) + (gw << 6) + gd];
        }
        xs[i] = f2b(v);
    }
    __syncthreads();

    f32x4 acc[8] = {};

    for (int pass = 0; pass < 2; ++pass) {
        const int rbase = pass * 32;
        {
            const int nt = wv & 1;
            short8 bfrag = *(const short8*)&uct[(rbase + nt * 16 + l15) * 32 + quad * 8];
            for (int mt = (wv >> 1); mt <= 40; mt += 4) {
                short8 afrag = *(const short8*)&xs[(mt * 16 + l15) * 32 + quad * 8];
                f32x4 c = {};
                c = __builtin_amdgcn_mfma_f32_16x16x32_bf16(afrag, bfrag, c, 0, 0, 0);
                const int col = nt * 16 + l15;
#pragma unroll
                for (int i2 = 0; i2 < 4; ++i2)
                    t0[(mt * 16 + quad * 4 + i2) * 32 + col] = f2b(c[i2]);
            }
        }
        __syncthreads();
        {
            float wh[3][8];
#pragma unroll
            for (int k = 0; k < 3; ++k) {
                const float4* pp_ = (const float4*)&ukf[k * 64 + rbase + rg * 8];
                float4 u0 = pp_[0], u1 = pp_[1];
                wh[k][0]=u0.x; wh[k][1]=u0.y; wh[k][2]=u0.z; wh[k][3]=u0.w;
                wh[k][4]=u1.x; wh[k][5]=u1.y; wh[k][6]=u1.z; wh[k][7]=u1.w;
            }
            for (int item = tid; item < 1728; item += NTH) {
                int q = item >> 2;
                float v[8] = {};
#pragma unroll
                for (int k = 0; k < 3; ++k) {
                    short8 sv = *(const short8*)&t0[(q + k * 108) * 32 + rg * 8];
#pragma unroll
                    for (int j = 0; j < 8; ++j) v[j] += wh[k][j] * b2f(sv[j]);
                }
                short8 o;
#pragma unroll
                for (int j = 0; j < 8; ++j) o[j] = f2b(v[j]);
                *(short8*)&t1[q * 32 + rg * 8] = o;
            }
        }
        __syncthreads();
        {
            float ww[3][8];
#pragma unroll
            for (int k = 0; k < 3; ++k) {
                const float4* pp_ = (const float4*)&ukf[(3 + k) * 64 + rbase + rg * 8];
                float4 u0 = pp_[0], u1 = pp_[1];
                ww[k][0]=u0.x; ww[k][1]=u0.y; ww[k][2]=u0.z; ww[k][3]=u0.w;
                ww[k][4]=u1.x; ww[k][5]=u1.y; ww[k][6]=u1.z; ww[k][7]=u1.w;
            }
            for (int item = tid; item < 1152; item += NTH) {
                int q2 = item >> 2;
                int oh = q2 / 72;
                int src = q2 + oh * 36;
                float v[8] = {};
#pragma unroll
                for (int k = 0; k < 3; ++k) {
                    short8 sv = *(const short8*)&t1[(src + k * 18) * 32 + rg * 8];
#pragma unroll
                    for (int j = 0; j < 8; ++j) v[j] += ww[k][j] * b2f(sv[j]);
                }
                short8 o;
#pragma unroll
                for (int j = 0; j < 8; ++j) o[j] = f2b(v[j]);
                *(short8*)&t0[q2 * 32 + rg * 8] = o;
            }
        }
        __syncthreads();
        {
            float wd[3][8];
#pragma unroll
            for (int k = 0; k < 3; ++k) {
                const float4* pp_ = (const float4*)&ukf[(6 + k) * 64 + rbase + rg * 8];
                float4 u0 = pp_[0], u1 = pp_[1];
                wd[k][0]=u0.x; wd[k][1]=u0.y; wd[k][2]=u0.z; wd[k][3]=u0.w;
                wd[k][4]=u1.x; wd[k][5]=u1.y; wd[k][6]=u1.z; wd[k][7]=u1.w;
            }
            for (int item = tid; item < 1024; item += NTH) {
                int pq = item >> 2;
                int src = pq + (pq >> 4) * 2;
                float v[8] = {};
#pragma unroll
                for (int k = 0; k < 3; ++k) {
                    short8 sv = *(const short8*)&t0[(src + k) * 32 + rg * 8];
#pragma unroll
                    for (int j = 0; j < 8; ++j) v[j] += wd[k][j] * b2f(sv[j]);
                }
                short8 o;
#pragma unroll
                for (int j = 0; j < 8; ++j) o[j] = f2b(v[j]);
                *(short8*)&t1[pq * 32 + rg * 8] = o;
            }
        }
        __syncthreads();
        {
            short8 bfr[4];
#pragma unroll
            for (int nt = 0; nt < 4; ++nt)
                bfr[nt] = *(const short8*)&ucot[(nt * 16 + l15) * 64 + rbase + quad * 8];
#pragma unroll
            for (int i = 0; i < 8; ++i) {
                int mt = wv * 2 + (i >> 2), nt = i & 3;
                short8 afr = *(const short8*)&t1[(mt * 16 + l15) * 32 + quad * 8];
                acc[i] = __builtin_amdgcn_mfma_f32_16x16x32_bf16(afr, bfr[nt], acc[i], 0, 0, 0);
            }
        }
    }

#pragma unroll
    for (int i = 0; i < 8; ++i) {
        int mt = wv * 2 + (i >> 2), nt = i & 3;
        int co = nt * 16 + l15;
        int oh = mt >> 2, ow = mt & 3;
        float bs = bias[co];
        float4 o4;
        o4.x = acc[i][0] + bs; o4.y = acc[i][1] + bs;
        o4.z = acc[i][2] + bs; o4.w = acc[i][3] + bs;
        long addr = ((long)(b * 64 + co) << 18) + ((long)(h0 + oh) << 12)
                  + ((w0 + ow) << 6) + (d0 + quad * 4);
        *(float4*)&out[addr] = o4;
    }
}

extern "C" void kernel_launch(void* const* d_in, const int* in_sizes, int n_in,
                              void* d_out, int out_size, void* d_ws, size_t ws_size,
                              hipStream_t stream) {
    const float* x    = (const float*)d_in[0];
    const float* Ukh  = (const float*)d_in[1];
    const float* Ukw  = (const float*)d_in[2];
    const float* Ukd  = (const float*)d_in[3];
    const float* Ucin = (const float*)d_in[4];
    const float* Uco  = (const float*)d_in[5];
    const float* bias = (const float*)d_in[6];
    float* out = (float*)d_out;

    const size_t needed = (size_t)2 * 262144 * 64 * 2;   // 64 MiB for t (bf16)
    if (ws_size >= needed) {
        short* t = (short*)d_ws;
        k1_channel<<<2048, 256, 0, stream>>>(x, Ucin, t);
        k2_conv_gemm<<<8192, 256, 0, stream>>>(t, Ukh, Ukw, Ukd, Uco, bias, out);
    } else {
        (void)hipFuncSetAttribute((const void*)cpd_conv3d_fused_fb,
                                  hipFuncAttributeMaxDynamicSharedMemorySize,
                                  SMEM_BYTES);
        cpd_conv3d_fused_fb<<<2048, NTH, SMEM_BYTES, stream>>>(
            x, Ukh, Ukw, Ukd, Ucin, Uco, bias, out);
    }
}